// Round 7
// baseline (70.985 us; speedup 1.0000x reference)
//
#include <hip/hip_runtime.h>

#define N_NODES 8192
#define WPR 256       // 32-bit words per bitmap row (8192 bits)
#define C 64
#define CAP 512       // per-row neighbor-list capacity (avg degree ~32)
#define GEMM_BLOCKS 2048   // 4 rows per 256-thread block

// ---------------------------------------------------------------------------
// K1 (block-role split, independent work in one launch):
//   blocks [0, GEMM_BLOCKS)           : y = x @ W^T (unscaled), 4 rows/block
//   blocks [GEMM_BLOCKS, 2*GEMM_BLOCKS): zero 4 KB of bitmap + 4 deg counters
// ---------------------------------------------------------------------------
__global__ __launch_bounds__(256) void init_gemm(const float* __restrict__ x,
                          const float* __restrict__ W,
                          float* __restrict__ y,
                          uint4* __restrict__ bm4,
                          int* __restrict__ deg) {
    int tid = threadIdx.x;
    if (blockIdx.x >= GEMM_BLOCKS) {
        int zb = blockIdx.x - GEMM_BLOCKS;
        bm4[zb * 256 + tid] = make_uint4(0u, 0u, 0u, 0u);
        if (tid < 4) deg[zb * 4 + tid] = 0;
        return;
    }
    // GEMM role: W staged transposed in LDS => lane o reads Wt[k*64+o],
    // consecutive across lanes, conflict-free.
    __shared__ float Wt[C * C];
    for (int i = tid; i < C * C; i += 256) {
        int o = i >> 6, k = i & 63;
        Wt[k * C + o] = W[i];
    }
    __syncthreads();
    int o = tid & 63;
    int r = blockIdx.x * 4 + (tid >> 6);
    const float* xr = x + (size_t)r * C;
    float acc = 0.0f;
#pragma unroll
    for (int k = 0; k < C; ++k) acc += xr[k] * Wt[k * C + o];
    y[(size_t)r * C + o] = acc;
}

// ---------------------------------------------------------------------------
// K2: edge scatter + dedup degree count. atomicOr is idempotent (set
//     semantics: duplicate edges collapse to 1); exactly the lane that flips
//     a bit 0->1 increments deg[r], so deg = post-dedup neighbor count —
//     deterministic. 2 edges per thread via int2 loads.
// ---------------------------------------------------------------------------
__global__ __launch_bounds__(256) void scatter_deg(const int* __restrict__ e, int E,
                            unsigned* __restrict__ bitmap,
                            int* __restrict__ deg) {
    int j = blockIdx.x * 256 + threadIdx.x;       // pair index
    int i = j * 2;
    if (i + 1 < E) {
        int2 rr = *(const int2*)(e + i);
        int2 cc = *(const int2*)(e + E + i);
        unsigned bit0 = 1u << (cc.x & 31);
        unsigned bit1 = 1u << (cc.y & 31);
        unsigned old0 = atomicOr(&bitmap[(size_t)rr.x * WPR + (cc.x >> 5)], bit0);
        unsigned old1 = atomicOr(&bitmap[(size_t)rr.y * WPR + (cc.y >> 5)], bit1);
        if (!(old0 & bit0)) atomicAdd(&deg[rr.x], 1);
        if (!(old1 & bit1)) atomicAdd(&deg[rr.y], 1);
    } else if (i < E) {
        int r = e[i], c = e[E + i];
        unsigned bit = 1u << (c & 31);
        unsigned old = atomicOr(&bitmap[(size_t)r * WPR + (c >> 5)], bit);
        if (!(old & bit)) atomicAdd(&deg[r], 1);
    }
}

// ---------------------------------------------------------------------------
// K3: out[r] = dinv[r] * ( sum_{c in row bits} dinv[c]*y[c] + dinv[r]*y[r] ) + b
//     with dinv[v] = rsqrt(deg[v]+1)  (+1 = added eye; a self-loop bit is
//     already in deg, giving the diagonal weight 2, matching the reference).
//     One wave per row, lane = channel. Phase A: lane-parallel bitmap scan ->
//     per-wave compact LDS column list (ascending => deterministic fp order,
//     no __syncthreads needed: list is wave-private). Phase B: 8-way split
//     accumulators pipeline the L2-hit gathers. Serial-scan fallback if a row
//     exceeds CAP (never at avg degree 32, kept for correctness).
// ---------------------------------------------------------------------------
__global__ __launch_bounds__(256) void spmm_kernel(const unsigned* __restrict__ bitmap,
                            const int* __restrict__ deg,
                            const float* __restrict__ y,
                            const float* __restrict__ b,
                            float* __restrict__ out) {
    __shared__ unsigned short list[4][CAP];
    int wave = threadIdx.x >> 6;
    int lane = threadIdx.x & 63;
    int r = blockIdx.x * 4 + wave;
    const uint4* row = (const uint4*)(bitmap + (size_t)r * WPR);
    uint4 v = row[lane];
    int myc = __popc(v.x) + __popc(v.y) + __popc(v.z) + __popc(v.w);

    // exclusive prefix sum of per-lane bit counts across the wave
    int pre = myc;
#pragma unroll
    for (int d = 1; d < 64; d <<= 1) {
        int t = __shfl_up(pre, d);
        if (lane >= d) pre += t;
    }
    int total = __shfl(pre, 63);
    int woff = pre - myc;
    bool uselist = (total <= CAP);
    unsigned short* L = list[wave];

    if (uselist) {
        int base = lane * 128;
        unsigned bits;
        bits = v.x;
        while (bits) { L[woff++] = (unsigned short)(base       + __builtin_ctz(bits)); bits &= bits - 1; }
        bits = v.y;
        while (bits) { L[woff++] = (unsigned short)(base + 32  + __builtin_ctz(bits)); bits &= bits - 1; }
        bits = v.z;
        while (bits) { L[woff++] = (unsigned short)(base + 64  + __builtin_ctz(bits)); bits &= bits - 1; }
        bits = v.w;
        while (bits) { L[woff++] = (unsigned short)(base + 96  + __builtin_ctz(bits)); bits &= bits - 1; }
    }
    // no __syncthreads: L is wave-private (compiler inserts lgkmcnt waits)

    float dr = rsqrtf((float)(deg[r] + 1));
    float acc = dr * y[(size_t)r * C + lane];   // eye term
    if (uselist) {
        float a0 = 0.f, a1 = 0.f, a2 = 0.f, a3 = 0.f;
        float a4 = 0.f, a5 = 0.f, a6 = 0.f, a7 = 0.f;
        int i = 0;
        for (; i + 8 <= total; i += 8) {
            int c0 = L[i], c1 = L[i+1], c2 = L[i+2], c3 = L[i+3];
            int c4 = L[i+4], c5 = L[i+5], c6 = L[i+6], c7 = L[i+7];
            float w0 = rsqrtf((float)(deg[c0] + 1));
            float w1 = rsqrtf((float)(deg[c1] + 1));
            float w2 = rsqrtf((float)(deg[c2] + 1));
            float w3 = rsqrtf((float)(deg[c3] + 1));
            float w4 = rsqrtf((float)(deg[c4] + 1));
            float w5 = rsqrtf((float)(deg[c5] + 1));
            float w6 = rsqrtf((float)(deg[c6] + 1));
            float w7 = rsqrtf((float)(deg[c7] + 1));
            a0 += w0 * y[c0 * C + lane];
            a1 += w1 * y[c1 * C + lane];
            a2 += w2 * y[c2 * C + lane];
            a3 += w3 * y[c3 * C + lane];
            a4 += w4 * y[c4 * C + lane];
            a5 += w5 * y[c5 * C + lane];
            a6 += w6 * y[c6 * C + lane];
            a7 += w7 * y[c7 * C + lane];
        }
        for (; i < total; ++i) {
            int c = L[i];
            acc += rsqrtf((float)(deg[c] + 1)) * y[c * C + lane];
        }
        acc += ((a0 + a1) + (a2 + a3)) + ((a4 + a5) + (a6 + a7));
    } else {
        // fallback: serial bitmap re-scan (correct for any degree)
        for (int w4i = 0; w4i < WPR / 4; ++w4i) {
            uint4 vv = row[w4i];
            int base = w4i * 128;
            unsigned bits;
            bits = vv.x; while (bits) { int c = base       + __builtin_ctz(bits); bits &= bits - 1; acc += rsqrtf((float)(deg[c] + 1)) * y[c * C + lane]; }
            bits = vv.y; while (bits) { int c = base + 32  + __builtin_ctz(bits); bits &= bits - 1; acc += rsqrtf((float)(deg[c] + 1)) * y[c * C + lane]; }
            bits = vv.z; while (bits) { int c = base + 64  + __builtin_ctz(bits); bits &= bits - 1; acc += rsqrtf((float)(deg[c] + 1)) * y[c * C + lane]; }
            bits = vv.w; while (bits) { int c = base + 96  + __builtin_ctz(bits); bits &= bits - 1; acc += rsqrtf((float)(deg[c] + 1)) * y[c * C + lane]; }
        }
    }
    out[(size_t)r * C + lane] = dr * acc + b[lane];
}

// ---------------------------------------------------------------------------
extern "C" void kernel_launch(void* const* d_in, const int* in_sizes, int n_in,
                              void* d_out, int out_size, void* d_ws, size_t ws_size,
                              hipStream_t stream) {
    const float* x  = (const float*)d_in[0];   // [8192, 64]
    const int*   ei = (const int*)d_in[1];     // [2, E] flat
    const float* W  = (const float*)d_in[2];   // [64, 64]
    const float* b  = (const float*)d_in[3];   // [64]
    float* out = (float*)d_out;                // [8192, 64]
    int E = in_sizes[1] / 2;

    // workspace layout: bitmap (8 MB) | deg (32 KB) | y (2 MB)
    unsigned* bitmap = (unsigned*)d_ws;
    int*   deg = (int*)((char*)d_ws + (size_t)N_NODES * WPR * 4);
    float* y   = (float*)(deg + N_NODES);

    init_gemm<<<2 * GEMM_BLOCKS, 256, 0, stream>>>(x, W, y, (uint4*)bitmap, deg);
    scatter_deg<<<(E / 2 + 255) / 256, 256, 0, stream>>>(ei, E, bitmap, deg);
    spmm_kernel<<<N_NODES / 4, 256, 0, stream>>>(bitmap, deg, y, b, out);
}

// Round 8
// 52.800 us; speedup vs baseline: 1.3444x; 1.3444x over previous
//
#include <hip/hip_runtime.h>

#define N_NODES 8192
#define WPR 256     // 32-bit words per bitmap row (8192 bits)
#define C 64
#define CAP 512     // per-row neighbor-list capacity (avg degree ~32)

// ---------------------------------------------------------------------------
// 0) Zero the 8 MB bitmap: one uint4 store/thread, fully coalesced.
// ---------------------------------------------------------------------------
__global__ __launch_bounds__(256) void zero_bitmap(uint4* __restrict__ bm4) {
    int i = blockIdx.x * 256 + threadIdx.x;
    bm4[i] = make_uint4(0u, 0u, 0u, 0u);
}

// ---------------------------------------------------------------------------
// 1) Edge scatter: NON-RETURNING atomicOr only (fire-and-forget; returning
//    atomics + dependent atomicAdd was the round-7 regression). Idempotent
//    => set semantics (duplicate edges collapse to 1), deterministic.
//    2 edges/thread via int2 loads.
// ---------------------------------------------------------------------------
__global__ __launch_bounds__(256) void scatter_edges(const int* __restrict__ e, int E,
                              unsigned* __restrict__ bitmap) {
    int i = (blockIdx.x * 256 + threadIdx.x) * 2;
    if (i + 1 < E) {
        int2 rr = *(const int2*)(e + i);
        int2 cc = *(const int2*)(e + E + i);
        atomicOr(&bitmap[(size_t)rr.x * WPR + (cc.x >> 5)], 1u << (cc.x & 31));
        atomicOr(&bitmap[(size_t)rr.y * WPR + (cc.y >> 5)], 1u << (cc.y & 31));
    } else if (i < E) {
        int r = e[i], c = e[E + i];
        atomicOr(&bitmap[(size_t)r * WPR + (c >> 5)], 1u << (c & 31));
    }
}

// ---------------------------------------------------------------------------
// 2) dinv[r] = (popcount(row r) + 1)^-0.5. +1 is the added eye; a self-loop
//    bit is already in the popcount (diag weight 2), matching the reference.
//    4 waves/block, one row per wave, lane popcounts one uint4.
// ---------------------------------------------------------------------------
__global__ __launch_bounds__(256) void degree_kernel(const unsigned* __restrict__ bitmap,
                               float* __restrict__ dinv) {
    int wave = threadIdx.x >> 6;
    int lane = threadIdx.x & 63;
    int r = blockIdx.x * 4 + wave;
    const uint4* row = (const uint4*)(bitmap + (size_t)r * WPR);
    uint4 v = row[lane];
    int cnt = __popc(v.x) + __popc(v.y) + __popc(v.z) + __popc(v.w);
#pragma unroll
    for (int off = 32; off; off >>= 1) cnt += __shfl_down(cnt, off);
    if (lane == 0) dinv[r] = rsqrtf((float)(cnt + 1));
}

// ---------------------------------------------------------------------------
// 3) ys = dinv[:,None] * (x @ W^T). Pre-scaling by dinv here removes the
//    per-neighbor dinv load/mult from the SpMM inner loop. W transposed in
//    LDS => lane o reads Wt[k*64+o], consecutive across lanes, conflict-free.
// ---------------------------------------------------------------------------
__global__ __launch_bounds__(256) void gemm_ys(const float* __restrict__ x,
                        const float* __restrict__ W,
                        const float* __restrict__ dinv,
                        float* __restrict__ ys) {
    __shared__ float Wt[C * C];
    int tid = threadIdx.x;
    for (int i = tid; i < C * C; i += 256) {
        int o = i >> 6, k = i & 63;
        Wt[k * C + o] = W[i];
    }
    __syncthreads();
    int o = tid & 63;
    int r = blockIdx.x * 4 + (tid >> 6);
    const float* xr = x + (size_t)r * C;
    float acc = 0.0f;
#pragma unroll
    for (int k = 0; k < C; ++k) acc += xr[k] * Wt[k * C + o];
    ys[(size_t)r * C + o] = dinv[r] * acc;
}

// ---------------------------------------------------------------------------
// 4) out[r] = dinv[r] * ( ys[r] + sum_{c in row bits} ys[c] ) + b
//    (ys[r] = dinv[r]*y[r] is exactly the eye term before the outer dinv[r].)
//    One wave/row, lane = channel. Phase A: lane-parallel bitmap scan ->
//    per-wave compact LDS column list (ascending => deterministic fp order;
//    NO __syncthreads — the list is wave-private). Phase B: 8-way split
//    accumulators pipeline the L2-hit gathers. Serial-scan fallback if a row
//    exceeds CAP (never at avg degree 32; kept for correctness).
// ---------------------------------------------------------------------------
__global__ __launch_bounds__(256) void spmm_kernel(const unsigned* __restrict__ bitmap,
                            const float* __restrict__ dinv,
                            const float* __restrict__ ys,
                            const float* __restrict__ b,
                            float* __restrict__ out) {
    __shared__ unsigned short list[4][CAP];
    int wave = threadIdx.x >> 6;
    int lane = threadIdx.x & 63;
    int r = blockIdx.x * 4 + wave;
    const uint4* row = (const uint4*)(bitmap + (size_t)r * WPR);
    uint4 v = row[lane];
    int myc = __popc(v.x) + __popc(v.y) + __popc(v.z) + __popc(v.w);

    // exclusive prefix sum of per-lane bit counts across the wave
    int pre = myc;
#pragma unroll
    for (int d = 1; d < 64; d <<= 1) {
        int t = __shfl_up(pre, d);
        if (lane >= d) pre += t;
    }
    int total = __shfl(pre, 63);
    int woff = pre - myc;
    bool uselist = (total <= CAP);
    unsigned short* L = list[wave];

    if (uselist) {
        int base = lane * 128;
        unsigned bits;
        bits = v.x;
        while (bits) { L[woff++] = (unsigned short)(base       + __builtin_ctz(bits)); bits &= bits - 1; }
        bits = v.y;
        while (bits) { L[woff++] = (unsigned short)(base + 32  + __builtin_ctz(bits)); bits &= bits - 1; }
        bits = v.z;
        while (bits) { L[woff++] = (unsigned short)(base + 64  + __builtin_ctz(bits)); bits &= bits - 1; }
        bits = v.w;
        while (bits) { L[woff++] = (unsigned short)(base + 96  + __builtin_ctz(bits)); bits &= bits - 1; }
    }
    // no barrier: L is wave-private; compiler inserts lgkmcnt waits

    float acc = ys[(size_t)r * C + lane];   // eye term
    if (uselist) {
        float a0 = 0.f, a1 = 0.f, a2 = 0.f, a3 = 0.f;
        float a4 = 0.f, a5 = 0.f, a6 = 0.f, a7 = 0.f;
        int i = 0;
        for (; i + 8 <= total; i += 8) {
            int c0 = L[i],   c1 = L[i+1], c2 = L[i+2], c3 = L[i+3];
            int c4 = L[i+4], c5 = L[i+5], c6 = L[i+6], c7 = L[i+7];
            a0 += ys[(size_t)c0 * C + lane];
            a1 += ys[(size_t)c1 * C + lane];
            a2 += ys[(size_t)c2 * C + lane];
            a3 += ys[(size_t)c3 * C + lane];
            a4 += ys[(size_t)c4 * C + lane];
            a5 += ys[(size_t)c5 * C + lane];
            a6 += ys[(size_t)c6 * C + lane];
            a7 += ys[(size_t)c7 * C + lane];
        }
        for (; i < total; ++i) acc += ys[(size_t)L[i] * C + lane];
        acc += ((a0 + a1) + (a2 + a3)) + ((a4 + a5) + (a6 + a7));
    } else {
        // fallback: serial bitmap re-scan (correct for any degree)
        for (int w4i = 0; w4i < WPR / 4; ++w4i) {
            uint4 vv = row[w4i];
            int base = w4i * 128;
            unsigned bits;
            bits = vv.x; while (bits) { int c = base       + __builtin_ctz(bits); bits &= bits - 1; acc += ys[(size_t)c * C + lane]; }
            bits = vv.y; while (bits) { int c = base + 32  + __builtin_ctz(bits); bits &= bits - 1; acc += ys[(size_t)c * C + lane]; }
            bits = vv.z; while (bits) { int c = base + 64  + __builtin_ctz(bits); bits &= bits - 1; acc += ys[(size_t)c * C + lane]; }
            bits = vv.w; while (bits) { int c = base + 96  + __builtin_ctz(bits); bits &= bits - 1; acc += ys[(size_t)c * C + lane]; }
        }
    }
    out[(size_t)r * C + lane] = dinv[r] * acc + b[lane];
}

// ---------------------------------------------------------------------------
extern "C" void kernel_launch(void* const* d_in, const int* in_sizes, int n_in,
                              void* d_out, int out_size, void* d_ws, size_t ws_size,
                              hipStream_t stream) {
    const float* x  = (const float*)d_in[0];   // [8192, 64]
    const int*   ei = (const int*)d_in[1];     // [2, E] flat
    const float* W  = (const float*)d_in[2];   // [64, 64]
    const float* b  = (const float*)d_in[3];   // [64]
    float* out = (float*)d_out;                // [8192, 64]
    int E = in_sizes[1] / 2;

    // workspace layout: bitmap (8 MB) | dinv (32 KB) | ys (2 MB)
    unsigned* bitmap = (unsigned*)d_ws;
    float* dinv = (float*)((char*)d_ws + (size_t)N_NODES * WPR * 4);
    float* ys   = dinv + N_NODES;

    zero_bitmap<<<2048, 256, 0, stream>>>((uint4*)bitmap);
    scatter_edges<<<(E / 2 + 255) / 256, 256, 0, stream>>>(ei, E, bitmap);
    degree_kernel<<<N_NODES / 4, 256, 0, stream>>>(bitmap, dinv);
    gemm_ys<<<N_NODES / 4, 256, 0, stream>>>(x, W, dinv, ys);
    spmm_kernel<<<N_NODES / 4, 256, 0, stream>>>(bitmap, dinv, ys, b, out);
}